// Round 1
// baseline (51.032 us; speedup 1.0000x reference)
//
#include <hip/hip_runtime.h>
#include <math.h>

#define EPS 1e-12f

__device__ __forceinline__ float smooth_clamp(float x, float lb, float rb, float sr) {
    // slope_l is always 0 in the reference's calls
    float t = (x - lb) / (rb - lb);
    float sig = 1.0f / (1.0f + __expf(-(4.0f * t - 2.0f)));
    float core = lb + (rb - lb) * sig;
    return core + sr * fmaxf(x - rb, 0.0f);
}

__global__ void __launch_bounds__(256) face_kernel(
    const float* __restrict__ pa, const float* __restrict__ pb, const float* __restrict__ pc,
    const float* __restrict__ rotz,
    const float* __restrict__ gsx, const float* __restrict__ gsy, const float* __restrict__ gsz,
    const float* __restrict__ color, const float* __restrict__ lop,
    float* __restrict__ out, int F)
{
    int i = blockIdx.x * blockDim.x + threadIdx.x;
    if (i >= F) return;

    // --- load vertices (12B/lane contiguous) ---
    float pax = pa[3*i+0], pay = pa[3*i+1], paz = pa[3*i+2];
    float pbx = pb[3*i+0], pby = pb[3*i+1], pbz = pb[3*i+2];
    float pcx = pc[3*i+0], pcy = pc[3*i+1], pcz = pc[3*i+2];

    // --- face frame ---
    float e1x = pbx - pax, e1y = pby - pay, e1z = pbz - paz;
    float e2x = pcx - pax, e2y = pcy - pay, e2z = pcz - paz;
    float nx = e1y*e2z - e1z*e2y;
    float ny = e1z*e2x - e1x*e2z;
    float nz = e1x*e2y - e1y*e2x;
    float nn = sqrtf(nx*nx + ny*ny + nz*nz);
    float area = 0.5f * nn;

    float e1n = sqrtf(e1x*e1x + e1y*e1y + e1z*e1z);
    float inv_e1 = 1.0f / (e1n + EPS);
    float axx = e1x*inv_e1, axy = e1y*inv_e1, axz = e1z*inv_e1;   // column ax
    float inv_n = 1.0f / (nn + EPS);
    float azx = nx*inv_n, azy = ny*inv_n, azz = nz*inv_n;         // column az
    // ay = cross(az, ax)
    float ayx = azy*axz - azz*axy;
    float ayy = azz*axx - azx*axz;
    float ayz = azx*axy - azy*axx;                                 // column ay

    // R columns = [ax ay az] -> m[r][c]
    float m00 = axx, m01 = ayx, m02 = azx;
    float m10 = axy, m11 = ayy, m12 = azy;
    float m20 = axz, m21 = ayz, m22 = azz;

    // --- rot mat -> quat (WXYZ), robust 4-case, argmax first-occurrence ---
    float tr = m00 + m11 + m22;
    float t0 = fmaxf(1.0f + tr,              1e-8f);
    float t1 = fmaxf(1.0f + m00 - m11 - m22, 1e-8f);
    float t2 = fmaxf(1.0f - m00 + m11 - m22, 1e-8f);
    float t3 = fmaxf(1.0f - m00 - m11 + m22, 1e-8f);

    int idx = 0; float best = tr;
    if (m00 > best) { best = m00; idx = 1; }
    if (m11 > best) { best = m11; idx = 2; }
    if (m22 > best) { idx = 3; }

    float qw, qx, qy, qz;
    if (idx == 0) {
        float s = 0.5f * rsqrtf(t0);
        qw = t0*s; qx = (m21-m12)*s; qy = (m02-m20)*s; qz = (m10-m01)*s;
    } else if (idx == 1) {
        float s = 0.5f * rsqrtf(t1);
        qw = (m21-m12)*s; qx = t1*s; qy = (m01+m10)*s; qz = (m02+m20)*s;
    } else if (idx == 2) {
        float s = 0.5f * rsqrtf(t2);
        qw = (m02-m20)*s; qx = (m01+m10)*s; qy = t2*s; qz = (m12+m21)*s;
    } else {
        float s = 0.5f * rsqrtf(t3);
        qw = (m10-m01)*s; qx = (m02+m20)*s; qy = (m12+m21)*s; qz = t3*s;
    }

    // --- compose with local z-rotation quaternion [c,0,0,s] ---
    float half = 0.5f * rotz[i];
    float sh, ch;
    __sincosf(half, &sh, &ch);
    float wqw = qw*ch - qz*sh;
    float wqx = qx*ch + qy*sh;
    float wqy = qy*ch - qx*sh;
    float wqz = qw*sh + qz*ch;

    // --- scales ---
    float sf = sqrtf(area);
    float sx = sf * smooth_clamp(__expf(gsx[i]), 0.1f,   3.0f, 0.005f);
    float sy = sf * smooth_clamp(__expf(gsy[i]), 0.1f,   3.0f, 0.005f);
    float sz =      smooth_clamp(sf * __expf(gsz[i]), 0.001f, 0.01f, 0.005f);

    float opacity = __expf(lop[i]);

    float cr = color[3*i+0], cg = color[3*i+1], cb = color[3*i+2];

    // centroid
    float tx = (pax + pbx + pcx) * (1.0f/3.0f);
    float ty = (pay + pby + pcy) * (1.0f/3.0f);
    float tz = (paz + pbz + pcz) * (1.0f/3.0f);

    // --- store 14 floats as 7x float2 (8B-aligned) ---
    float2* o2 = reinterpret_cast<float2*>(out + 14*i);
    o2[0] = make_float2(tx,  ty);
    o2[1] = make_float2(tz,  wqw);
    o2[2] = make_float2(wqx, wqy);
    o2[3] = make_float2(wqz, sx);
    o2[4] = make_float2(sy,  sz);
    o2[5] = make_float2(cr,  cg);
    o2[6] = make_float2(cb,  opacity);
}

extern "C" void kernel_launch(void* const* d_in, const int* in_sizes, int n_in,
                              void* d_out, int out_size, void* d_ws, size_t ws_size,
                              hipStream_t stream) {
    const float* pa   = (const float*)d_in[0];
    const float* pb   = (const float*)d_in[1];
    const float* pc   = (const float*)d_in[2];
    const float* rotz = (const float*)d_in[3];
    const float* gsx  = (const float*)d_in[4];
    const float* gsy  = (const float*)d_in[5];
    const float* gsz  = (const float*)d_in[6];
    const float* col  = (const float*)d_in[7];
    const float* lop  = (const float*)d_in[8];
    float* out = (float*)d_out;

    int F = in_sizes[3];  // gp_rot_z has F elements
    int block = 256;
    int grid = (F + block - 1) / block;
    face_kernel<<<grid, block, 0, stream>>>(pa, pb, pc, rotz, gsx, gsy, gsz, col, lop, out, F);
}

// Round 3
// 40.703 us; speedup vs baseline: 1.2538x; 1.2538x over previous
//
#include <hip/hip_runtime.h>
#include <math.h>

#define EPS 1e-12f

typedef float f32x4 __attribute__((ext_vector_type(4)));

__device__ __forceinline__ float smooth_clamp(float x, float lb, float rb, float sr) {
    // slope_l is always 0 in the reference's calls
    float t = (x - lb) / (rb - lb);
    float sig = 1.0f / (1.0f + __expf(-(4.0f * t - 2.0f)));
    float core = lb + (rb - lb) * sig;
    return core + sr * fmaxf(x - rb, 0.0f);
}

__global__ void __launch_bounds__(256) face_kernel(
    const float* __restrict__ pa, const float* __restrict__ pb, const float* __restrict__ pc,
    const float* __restrict__ rotz,
    const float* __restrict__ gsx, const float* __restrict__ gsy, const float* __restrict__ gsz,
    const float* __restrict__ color, const float* __restrict__ lop,
    float* __restrict__ out, int F)
{
    __shared__ float s[256 * 14];   // 14336 B

    const int tid = threadIdx.x;
    const int blockBase = blockIdx.x * 256;
    const int i = blockBase + tid;
    const int count = min(256, F - blockBase);   // valid threads in this block

    if (tid < count) {
        // --- load vertices (12B/lane contiguous) ---
        float pax = pa[3*i+0], pay = pa[3*i+1], paz = pa[3*i+2];
        float pbx = pb[3*i+0], pby = pb[3*i+1], pbz = pb[3*i+2];
        float pcx = pc[3*i+0], pcy = pc[3*i+1], pcz = pc[3*i+2];

        // --- face frame ---
        float e1x = pbx - pax, e1y = pby - pay, e1z = pbz - paz;
        float e2x = pcx - pax, e2y = pcy - pay, e2z = pcz - paz;
        float nx = e1y*e2z - e1z*e2y;
        float ny = e1z*e2x - e1x*e2z;
        float nz = e1x*e2y - e1y*e2x;
        float nn = sqrtf(nx*nx + ny*ny + nz*nz);
        float area = 0.5f * nn;

        float e1n = sqrtf(e1x*e1x + e1y*e1y + e1z*e1z);
        float inv_e1 = 1.0f / (e1n + EPS);
        float axx = e1x*inv_e1, axy = e1y*inv_e1, axz = e1z*inv_e1;   // column ax
        float inv_n = 1.0f / (nn + EPS);
        float azx = nx*inv_n, azy = ny*inv_n, azz = nz*inv_n;         // column az
        // ay = cross(az, ax)
        float ayx = azy*axz - azz*axy;
        float ayy = azz*axx - azx*axz;
        float ayz = azx*axy - azy*axx;                                 // column ay

        // R columns = [ax ay az] -> m[r][c]
        float m00 = axx, m01 = ayx, m02 = azx;
        float m10 = axy, m11 = ayy, m12 = azy;
        float m20 = axz, m21 = ayz, m22 = azz;

        // --- rot mat -> quat (WXYZ), robust 4-case, argmax first-occurrence ---
        float tr = m00 + m11 + m22;
        float t0 = fmaxf(1.0f + tr,              1e-8f);
        float t1 = fmaxf(1.0f + m00 - m11 - m22, 1e-8f);
        float t2 = fmaxf(1.0f - m00 + m11 - m22, 1e-8f);
        float t3 = fmaxf(1.0f - m00 - m11 + m22, 1e-8f);

        int idx = 0; float best = tr;
        if (m00 > best) { best = m00; idx = 1; }
        if (m11 > best) { best = m11; idx = 2; }
        if (m22 > best) { idx = 3; }

        float qw, qx, qy, qz;
        if (idx == 0) {
            float sN = 0.5f * rsqrtf(t0);
            qw = t0*sN; qx = (m21-m12)*sN; qy = (m02-m20)*sN; qz = (m10-m01)*sN;
        } else if (idx == 1) {
            float sN = 0.5f * rsqrtf(t1);
            qw = (m21-m12)*sN; qx = t1*sN; qy = (m01+m10)*sN; qz = (m02+m20)*sN;
        } else if (idx == 2) {
            float sN = 0.5f * rsqrtf(t2);
            qw = (m02-m20)*sN; qx = (m01+m10)*sN; qy = t2*sN; qz = (m12+m21)*sN;
        } else {
            float sN = 0.5f * rsqrtf(t3);
            qw = (m10-m01)*sN; qx = (m02+m20)*sN; qy = (m12+m21)*sN; qz = t3*sN;
        }

        // --- compose with local z-rotation quaternion [c,0,0,s] ---
        float half = 0.5f * rotz[i];
        float sh, ch;
        __sincosf(half, &sh, &ch);
        float wqw = qw*ch - qz*sh;
        float wqx = qx*ch + qy*sh;
        float wqy = qy*ch - qx*sh;
        float wqz = qw*sh + qz*ch;

        // --- scales ---
        float sf = sqrtf(area);
        float sx = sf * smooth_clamp(__expf(gsx[i]), 0.1f,   3.0f, 0.005f);
        float sy = sf * smooth_clamp(__expf(gsy[i]), 0.1f,   3.0f, 0.005f);
        float sz =      smooth_clamp(sf * __expf(gsz[i]), 0.001f, 0.01f, 0.005f);

        float opacity = __expf(lop[i]);

        float cr = color[3*i+0], cg = color[3*i+1], cb = color[3*i+2];

        // centroid
        float tx = (pax + pbx + pcx) * (1.0f/3.0f);
        float ty = (pay + pby + pcy) * (1.0f/3.0f);
        float tz = (paz + pbz + pcz) * (1.0f/3.0f);

        // stage 14 results in LDS (stride-14 write: ~4-way conflict, cheap)
        float* sr = &s[tid * 14];
        sr[0]  = tx;  sr[1]  = ty;  sr[2]  = tz;
        sr[3]  = wqw; sr[4]  = wqx; sr[5]  = wqy; sr[6]  = wqz;
        sr[7]  = sx;  sr[8]  = sy;  sr[9]  = sz;
        sr[10] = cr;  sr[11] = cg;  sr[12] = cb;  sr[13] = opacity;
    }

    __syncthreads();

    // --- coalesced block output: count*14 floats contiguous, as float4 ---
    const int nfloat = count * 14;
    float* obase = out + (long)blockBase * 14;   // 16B-aligned (14336*blockIdx)
    const int nf4 = nfloat >> 2;
    for (int j = tid; j < nf4; j += 256) {
        f32x4 v = *reinterpret_cast<const f32x4*>(&s[4*j]);
        __builtin_nontemporal_store(v, reinterpret_cast<f32x4*>(obase) + j);
    }
    const int rem = nfloat & 3;
    if (tid < rem) {
        obase[nf4*4 + tid] = s[nf4*4 + tid];
    }
}

extern "C" void kernel_launch(void* const* d_in, const int* in_sizes, int n_in,
                              void* d_out, int out_size, void* d_ws, size_t ws_size,
                              hipStream_t stream) {
    const float* pa   = (const float*)d_in[0];
    const float* pb   = (const float*)d_in[1];
    const float* pc   = (const float*)d_in[2];
    const float* rotz = (const float*)d_in[3];
    const float* gsx  = (const float*)d_in[4];
    const float* gsy  = (const float*)d_in[5];
    const float* gsz  = (const float*)d_in[6];
    const float* col  = (const float*)d_in[7];
    const float* lop  = (const float*)d_in[8];
    float* out = (float*)d_out;

    int F = in_sizes[3];  // gp_rot_z has F elements
    int block = 256;
    int grid = (F + block - 1) / block;
    face_kernel<<<grid, block, 0, stream>>>(pa, pb, pc, rotz, gsx, gsy, gsz, col, lop, out, F);
}